// Round 3
// baseline (21696.478 us; speedup 1.0000x reference)
//
#include <hip/hip_runtime.h>
#include <hip/hip_bf16.h>

// =====================================================================
// PlantLSTM R3: weight-resident (R2) + cheap sync + latency hiding.
//  - 16 groups x 16 WGs; WG owns 64 gate rows; weights in LDS all run.
//  - Sync fix vs R2: polls are RELAXED agent atomics (no per-iteration
//    acquire cache ops), one acquire fence after match; one release
//    fence per post. R2's acquire-spin was ~33us/step of fabric storms.
//  - Pipeline: h0 RT hidden under L1's h1(t-1) half (local from prev
//    gather); h1 RT hidden under L0(t+1) x+h0 chunks; pv(t-1) consumed
//    as L0's final K-chunk at loop head (only ~1 RT/step exposed).
//  - Protocol unchanged from R2 (validated): exact-match ==t+1 flags,
//    2-slot parity ring; producer run-ahead bounded by all-to-all flag
//    dependency, so slot overwrite is provably after all consumers read.
// =====================================================================

#define TSTEPS 512
#define NIN    32

typedef _Float16 h2 __attribute__((ext_vector_type(2)));
typedef unsigned long long ull;

#if __has_builtin(__builtin_amdgcn_fdot2)
#define FDOT2(a, b, c) __builtin_amdgcn_fdot2((a), (b), (c), false)
#else
#define FDOT2(a, b, c) ((c) + (float)(a).x * (float)(b).x + (float)(a).y * (float)(b).y)
#endif

__device__ __forceinline__ float sigm(float x) { return 1.0f / (1.0f + __expf(-x)); }
__device__ __forceinline__ float tanhf_(float x) {
    float e = __expf(2.0f * x);
    return 1.0f - 2.0f / (e + 1.0f);
}

// ---- workspace layout (bytes), unchanged from R2 ----
#define W0T_OFF 0u
#define W1T_OFF 606208u
#define F1T_OFF 1654784u
#define F2T_OFF 1720320u
#define HX0_OFF 2097152u
#define HX1_OFF 2359296u
#define PVX_OFF 2621440u
#define FLG_OFF 2629632u
#define WS_NEED 2678784u

#define W0S 592
#define W1S 1040
#define X0S 608
#define X1S 1040

// ------------------------- prep kernels (unchanged) -------------------------
__global__ void prep_w(const float* __restrict__ Wih0, const float* __restrict__ Whh0,
                       const float* __restrict__ Wih1, const float* __restrict__ Whh1,
                       char* __restrict__ ws) {
    int gid = blockIdx.x * 256 + threadIdx.x;
    _Float16* w0 = (_Float16*)(ws + W0T_OFF);
    _Float16* w1 = (_Float16*)(ws + W1T_OFF);
    if (gid < 16 * 64 * 296) {
        int k = gid % 296;
        int rest = gid / 296;
        int rl = rest & 63, j = rest >> 6;
        int row = (rl >> 4) * 256 + j * 16 + (rl & 15);
        float v;
        if (k < 32) v = Wih0[row * 72 + k];
        else if (k < 288) v = Whh0[row * 256 + (k - 32)];
        else v = Wih0[row * 72 + 32 + (k - 288)];
        w0[(j * 64 + rl) * 296 + k] = (_Float16)v;
    } else {
        int gid2 = gid - 16 * 64 * 296;
        if (gid2 < 16 * 64 * 512) {
            int k = gid2 & 511;
            int rest = gid2 >> 9;
            int rl = rest & 63, j = rest >> 6;
            int row = (rl >> 4) * 256 + j * 16 + (rl & 15);
            float v = (k < 256) ? Wih1[row * 256 + k] : Whh1[row * 256 + (k - 256)];
            w1[(j * 64 + rl) * 512 + k] = (_Float16)v;
        }
    }
}

__global__ void prep_fc(const float* __restrict__ fc1w, const float* __restrict__ fc2w,
                        char* __restrict__ ws) {
    int gid = blockIdx.x * 256 + threadIdx.x;
    _Float16* f1 = (_Float16*)(ws + F1T_OFF);
    _Float16* f2 = (_Float16*)(ws + F2T_OFF);
    if (gid < 32768) {
        int e = gid & 63, ks = (gid >> 6) & 3, r = gid >> 8;
        f1[gid] = (_Float16)fc1w[r * 256 + ks * 64 + e];
    } else if (gid < 32768 + 1024) {
        int i = gid - 32768;
        f2[i] = (_Float16)fc2w[i];
    }
}

// ------------------------- sync helpers -------------------------
__device__ __forceinline__ void post_flag(unsigned* f, unsigned v) {
    __builtin_amdgcn_fence(__ATOMIC_RELEASE, "agent");  // drain data stores
    __hip_atomic_store(f, v, __ATOMIC_RELAXED, __HIP_MEMORY_SCOPE_AGENT);
}
__device__ __forceinline__ void poll_flag(unsigned* f, unsigned want) {
    int spins = 0;
    while (__hip_atomic_load(f, __ATOMIC_RELAXED, __HIP_MEMORY_SCOPE_AGENT) != want) {
        if (++spins == 512) {  // safety valve: refresh caches if relaxed is sticky
            spins = 0;
            (void)__hip_atomic_load(f, __ATOMIC_ACQUIRE, __HIP_MEMORY_SCOPE_AGENT);
        }
    }
}
#define FENCE_ACQ() __builtin_amdgcn_fence(__ATOMIC_ACQUIRE, "agent")

// ------------------------- gate accumulation -------------------------
// lane = gate row; chunks [c0, cend) step cstep; 16 batches; atomicAdd to g.
__device__ __forceinline__ void accum(const char* __restrict__ w, int WS,
                                      const char* __restrict__ x, int XS,
                                      int c0, int cstep, int cend,
                                      float* g, int lane) {
    float acc[16];
#pragma unroll
    for (int b = 0; b < 16; ++b) acc[b] = 0.0f;
    for (int c = c0; c < cend; c += cstep) {
        float4 wv4 = *(const float4*)(w + lane * WS + c * 16);
        h2 a0 = __builtin_bit_cast(h2, wv4.x), a1 = __builtin_bit_cast(h2, wv4.y);
        h2 a2 = __builtin_bit_cast(h2, wv4.z), a3 = __builtin_bit_cast(h2, wv4.w);
#pragma unroll
        for (int b = 0; b < 16; ++b) {
            float4 xv = *(const float4*)(x + b * XS + c * 16);
            acc[b] = FDOT2(a0, __builtin_bit_cast(h2, xv.x), acc[b]);
            acc[b] = FDOT2(a1, __builtin_bit_cast(h2, xv.y), acc[b]);
            acc[b] = FDOT2(a2, __builtin_bit_cast(h2, xv.z), acc[b]);
            acc[b] = FDOT2(a3, __builtin_bit_cast(h2, xv.w), acc[b]);
        }
    }
#pragma unroll
    for (int b = 0; b < 16; ++b) atomicAdd(&g[b * 64 + lane], acc[b]);
}

// ------------------------- main kernel -------------------------
__global__ __launch_bounds__(512) void lstm_main(
    const float* __restrict__ x_cv, const float* __restrict__ pv_init,
    const int* __restrict__ scen, const float* __restrict__ emb_table,
    const float* __restrict__ Wih0, const float* __restrict__ b_ih0,
    const float* __restrict__ b_hh0, const float* __restrict__ b_ih1,
    const float* __restrict__ b_hh1, const float* __restrict__ fc1_b,
    const float* __restrict__ fc2_b, char* __restrict__ ws,
    float* __restrict__ out) {
    struct __align__(16) SM {
        char w0[64 * W0S];
        char w1[64 * W1S];
        char xt0[16 * X0S];      // [b][x(32)|h0(256)|pv(8) f16 + pad]
        char xt1[16 * X1S];      // [b][h0(256)|h1(256) f16 + pad]
        float gates0[16][64];
        float gates1[16][64];
        float biasE[16][64];
        float bias1[64];
        _Float16 htmp[16][16];
        float embs[16][32];
        float fc1o[128];
        int scen_l[16];
    };
    __shared__ SM sm;

    const int tid = threadIdx.x;
    const int lane = tid & 63;
    const int wv = tid >> 6;
    const int bid = blockIdx.x;
    const int g = (bid & 7) * 2 + ((bid >> 3) & 1);
    const int j = bid >> 4;
    const int B0 = g * 16;

    const char* w0g = ws + W0T_OFF + (unsigned)j * (64u * 296u * 2u);
    const char* w1g = ws + W1T_OFF + (unsigned)j * (64u * 512u * 2u);
    ull* hx0 = (ull*)(ws + HX0_OFF) + (unsigned)g * 2u * 16u * 64u;
    ull* hx1 = (ull*)(ws + HX1_OFF) + (unsigned)g * 2u * 16u * 64u;
    ull* pvx = (ull*)(ws + PVX_OFF) + (unsigned)g * 2u * 16u * 2u;
    unsigned* flg = (unsigned*)(ws + FLG_OFF) + (unsigned)g * 16u * 3u * 16u;

    // ---- phase 0 ----
    if (tid < 16) sm.scen_l[tid] = scen[B0 + tid];
    if (tid == 0) {
        __hip_atomic_store(&flg[(j * 3 + 0) * 16], 0u, __ATOMIC_RELAXED, __HIP_MEMORY_SCOPE_AGENT);
        __hip_atomic_store(&flg[(j * 3 + 1) * 16], 0u, __ATOMIC_RELAXED, __HIP_MEMORY_SCOPE_AGENT);
        __hip_atomic_store(&flg[(j * 3 + 2) * 16], 0u, __ATOMIC_RELAXED, __HIP_MEMORY_SCOPE_AGENT);
    }
    __syncthreads();

    // ---- phase 1: embs, zero xt, weights -> LDS ----
    {
        int b = tid >> 5, e = tid & 31;
        sm.embs[b][e] = emb_table[sm.scen_l[b] * 32 + e];
    }
    for (int idx = tid; idx < (16 * X0S) / 8; idx += 512) ((ull*)sm.xt0)[idx] = 0ull;
    for (int idx = tid; idx < (16 * X1S) / 8; idx += 512) ((ull*)sm.xt1)[idx] = 0ull;
    for (int idx = tid; idx < 64 * 37; idx += 512) {
        int r = idx / 37, c = idx - r * 37;
        *(float4*)(&sm.w0[r * W0S + c * 16]) = *(const float4*)(w0g + r * 592 + c * 16);
    }
    for (int idx = tid; idx < 64 * 64; idx += 512) {
        int r = idx >> 6, c = idx & 63;
        *(float4*)(&sm.w1[r * W1S + c * 16]) = *(const float4*)(w1g + r * 1024 + c * 16);
    }
    __syncthreads();

    // ---- phase 2: biases, FC register weights ----
    for (int idx = tid; idx < 1024; idx += 512) {
        int b = idx >> 6, rl = idx & 63;
        int row = (rl >> 4) * 256 + j * 16 + (rl & 15);
        float s = b_ih0[row] + b_hh0[row];
        for (int e = 0; e < 32; ++e) s += sm.embs[b][e] * Wih0[row * 72 + 40 + e];
        sm.biasE[b][rl] = s;
    }
    if (tid < 64) {
        int row = (tid >> 4) * 256 + j * 16 + (tid & 15);
        sm.bias1[tid] = b_ih1[row] + b_hh1[row];
    }
    float4 f1w[8];
    {
        const char* f1g = ws + F1T_OFF + (unsigned)tid * 128u;
#pragma unroll
        for (int q = 0; q < 8; ++q) f1w[q] = *(const float4*)(f1g + q * 16);
    }
    float f2w[16];
    if (wv == 0) {
        int jo = lane >> 3, ks2 = lane & 7;
        const _Float16* f2g = (const _Float16*)(ws + F2T_OFF) + jo * 128 + ks2 * 16;
#pragma unroll
        for (int q = 0; q < 16; ++q) f2w[q] = (float)f2g[q];
    }
    const float fc2b_r = (wv == 0) ? fc2_b[lane >> 3] : 0.0f;
    const float fc1b_r = fc1_b[tid >> 2];
    float c0 = 0.0f, c1 = 0.0f;
    __syncthreads();

    // ---- prologue: gates init, stage x(0), L0(0) x+h0 chunks ----
    for (int idx = tid; idx < 1024; idx += 512) {
        int b = idx >> 6, rl = idx & 63;
        sm.gates0[b][rl] = sm.biasE[b][rl];
        sm.gates1[b][rl] = sm.bias1[rl];
    }
    {
        int b = tid >> 5, k = tid & 31;
        float xv = x_cv[((B0 + b) * TSTEPS + 0) * NIN + k];
        *(_Float16*)(&sm.xt0[b * X0S + k * 2]) = (_Float16)xv;
    }
    __syncthreads();
    accum(sm.w0, W0S, sm.xt0, X0S, wv, 8, 36, &sm.gates0[0][0], lane);

    // ==================== time loop ====================
    for (int t = 0; t < TSTEPS; ++t) {
        const int par = t & 1;

        // ---- head: pv(t-1) as L0's final chunk (wave0 only) ----
        if (wv == 0) {
            if (t == 0) {
                // 64 lanes cover 16 b x 4 h2: lane -> b=lane>>2, pair=lane&3
                int b = lane >> 2, p = lane & 3;
                h2 v;
                v.x = (_Float16)pv_init[(B0 + b) * 8 + p * 2];
                v.y = (_Float16)pv_init[(B0 + b) * 8 + p * 2 + 1];
                *(h2*)(&sm.xt0[b * X0S + 576 + p * 4]) = v;
            } else {
                if (lane < 16) poll_flag(&flg[(lane * 3 + 2) * 16], (unsigned)t);
                FENCE_ACQ();
                if (lane < 32) {
                    int b = lane >> 1, half = lane & 1;
                    int pp = (t - 1) & 1;
                    ull v = __hip_atomic_load(&pvx[(pp * 16 + b) * 2 + half],
                                              __ATOMIC_RELAXED, __HIP_MEMORY_SCOPE_AGENT);
                    *(ull*)(&sm.xt0[b * X0S + 576 + half * 8]) = v;
                }
            }
            accum(sm.w0, W0S, sm.xt0, X0S, 36, 8, 37, &sm.gates0[0][0], lane);
        }
        __syncthreads();  // B1

        // ---- cell 0 ----
        if (tid < 256) {
            int ui = tid & 15, b = tid >> 4;
            float gi = sm.gates0[b][ui], gf = sm.gates0[b][16 + ui];
            float gc = sm.gates0[b][32 + ui], go = sm.gates0[b][48 + ui];
            c0 = sigm(gf) * c0 + sigm(gi) * tanhf_(gc);
            sm.htmp[b][ui] = (_Float16)(sigm(go) * tanhf_(c0));
        }
        __syncthreads();  // B2

        // ---- post h0; stage x(t+1); L1 h1(t-1)-half; poll h0 ----
        if (wv == 0) {
            ull v = *(const ull*)(&sm.htmp[lane >> 2][(lane & 3) * 4]);
            __hip_atomic_store(&hx0[(par * 16 + j) * 64 + lane], v, __ATOMIC_RELAXED,
                               __HIP_MEMORY_SCOPE_AGENT);
            if (lane == 0) post_flag(&flg[(j * 3 + 0) * 16], (unsigned)(t + 1));
        }
        if (t < TSTEPS - 1) {
            int b = tid >> 5, k = tid & 31;
            float xv = x_cv[((B0 + b) * TSTEPS + t + 1) * NIN + k];
            *(_Float16*)(&sm.xt0[b * X0S + k * 2]) = (_Float16)xv;
        }
        accum(sm.w1, W1S, sm.xt1, X1S, 32 + wv, 8, 64, &sm.gates1[0][0], lane);
        if (wv == 0) {
            if (lane < 16) poll_flag(&flg[(lane * 3 + 0) * 16], (unsigned)(t + 1));
            FENCE_ACQ();
        }
        __syncthreads();  // B3

        // ---- gather h0 -> xt1[0:256] & xt0 h0-part; gates0 <- biasE ----
        for (int idx = tid; idx < 1024; idx += 512) {
            int jj = idx >> 6, l = idx & 63;
            ull v = __hip_atomic_load(&hx0[(par * 16 + jj) * 64 + l], __ATOMIC_RELAXED,
                                      __HIP_MEMORY_SCOPE_AGENT);
            int b = l >> 2, u = jj * 16 + (l & 3) * 4;
            *(ull*)(&sm.xt1[b * X1S + u * 2]) = v;
            *(ull*)(&sm.xt0[b * X0S + (32 + u) * 2]) = v;
        }
        for (int idx = tid; idx < 1024; idx += 512) {
            int b = idx >> 6, rl = idx & 63;
            sm.gates0[b][rl] = sm.biasE[b][rl];
        }
        __syncthreads();  // B4

        // ---- L1 h0-half ----
        accum(sm.w1, W1S, sm.xt1, X1S, wv, 8, 32, &sm.gates1[0][0], lane);
        __syncthreads();  // B5

        // ---- cell 1 ----
        if (tid < 256) {
            int ui = tid & 15, b = tid >> 4;
            float gi = sm.gates1[b][ui], gf = sm.gates1[b][16 + ui];
            float gc = sm.gates1[b][32 + ui], go = sm.gates1[b][48 + ui];
            c1 = sigm(gf) * c1 + sigm(gi) * tanhf_(gc);
            sm.htmp[b][ui] = (_Float16)(sigm(go) * tanhf_(c1));
        }
        __syncthreads();  // B6

        // ---- post h1; gates1 <- bias1; L0(t+1) x+h0 chunks; poll h1 ----
        if (wv == 0) {
            ull v = *(const ull*)(&sm.htmp[lane >> 2][(lane & 3) * 4]);
            __hip_atomic_store(&hx1[(par * 16 + j) * 64 + lane], v, __ATOMIC_RELAXED,
                               __HIP_MEMORY_SCOPE_AGENT);
            if (lane == 0) post_flag(&flg[(j * 3 + 1) * 16], (unsigned)(t + 1));
        }
        for (int idx = tid; idx < 1024; idx += 512) {
            int b = idx >> 6, rl = idx & 63;
            sm.gates1[b][rl] = sm.bias1[rl];
        }
        if (t < TSTEPS - 1) {
            if (wv > 0) accum(sm.w0, W0S, sm.xt0, X0S, wv - 1, 7, 35, &sm.gates0[0][0], lane);
            else accum(sm.w0, W0S, sm.xt0, X0S, 35, 7, 36, &sm.gates0[0][0], lane);
        }
        if (wv == 0) {
            if (lane < 16) poll_flag(&flg[(lane * 3 + 1) * 16], (unsigned)(t + 1));
            FENCE_ACQ();
        }
        __syncthreads();  // B7

        // ---- gather h1 -> xt1[256:512] ----
        for (int idx = tid; idx < 1024; idx += 512) {
            int jj = idx >> 6, l = idx & 63;
            ull v = __hip_atomic_load(&hx1[(par * 16 + jj) * 64 + l], __ATOMIC_RELAXED,
                                      __HIP_MEMORY_SCOPE_AGENT);
            int b = l >> 2, u = jj * 16 + (l & 3) * 4;
            *(ull*)(&sm.xt1[b * X1S + (256 + u) * 2]) = v;
        }
        __syncthreads();  // B8

        // ---- FC1 (own batch j) ----
        {
            int row = tid >> 2, ks = tid & 3;
            float a = 0.0f;
#pragma unroll
            for (int q = 0; q < 8; ++q) {
                float4 xv = *(const float4*)(&sm.xt1[j * X1S + (256 + ks * 64 + q * 8) * 2]);
                a = FDOT2(__builtin_bit_cast(h2, f1w[q].x), __builtin_bit_cast(h2, xv.x), a);
                a = FDOT2(__builtin_bit_cast(h2, f1w[q].y), __builtin_bit_cast(h2, xv.y), a);
                a = FDOT2(__builtin_bit_cast(h2, f1w[q].z), __builtin_bit_cast(h2, xv.z), a);
                a = FDOT2(__builtin_bit_cast(h2, f1w[q].w), __builtin_bit_cast(h2, xv.w), a);
            }
            a += __shfl_xor(a, 1);
            a += __shfl_xor(a, 2);
            if (ks == 0) sm.fc1o[row] = fmaxf(a + fc1b_r, 0.0f);
        }
        __syncthreads();  // B9

        // ---- FC2 (wave0) -> out + pv post ----
        if (wv == 0) {
            int jo = lane >> 3, ks2 = lane & 7;
            float a = 0.0f;
#pragma unroll
            for (int q = 0; q < 4; ++q) {
                float4 xv = *(const float4*)(&sm.fc1o[ks2 * 16 + q * 4]);
                a += f2w[q * 4 + 0] * xv.x + f2w[q * 4 + 1] * xv.y +
                     f2w[q * 4 + 2] * xv.z + f2w[q * 4 + 3] * xv.w;
            }
            a += __shfl_xor(a, 1);
            a += __shfl_xor(a, 2);
            a += __shfl_xor(a, 4);
            float av = a + fc2b_r;
            if (ks2 == 0) out[((B0 + j) * TSTEPS + t) * 8 + jo] = av;
            float p0 = __shfl(av, 0), p1 = __shfl(av, 8), p2 = __shfl(av, 16), p3 = __shfl(av, 24);
            float p4 = __shfl(av, 32), p5 = __shfl(av, 40), p6 = __shfl(av, 48), p7 = __shfl(av, 56);
            if (lane == 0) {
                h2 q0, q1, q2, q3;
                q0.x = (_Float16)p0; q0.y = (_Float16)p1;
                q1.x = (_Float16)p2; q1.y = (_Float16)p3;
                q2.x = (_Float16)p4; q2.y = (_Float16)p5;
                q3.x = (_Float16)p6; q3.y = (_Float16)p7;
                ull v0 = ((ull)__builtin_bit_cast(unsigned, q1) << 32) |
                         __builtin_bit_cast(unsigned, q0);
                ull v1 = ((ull)__builtin_bit_cast(unsigned, q3) << 32) |
                         __builtin_bit_cast(unsigned, q2);
                __hip_atomic_store(&pvx[(par * 16 + j) * 2 + 0], v0, __ATOMIC_RELAXED,
                                   __HIP_MEMORY_SCOPE_AGENT);
                __hip_atomic_store(&pvx[(par * 16 + j) * 2 + 1], v1, __ATOMIC_RELAXED,
                                   __HIP_MEMORY_SCOPE_AGENT);
                post_flag(&flg[(j * 3 + 2) * 16], (unsigned)(t + 1));
            }
        }
        // next head's B1 guards gates0 for cell0(t+1)
    }
}

// ------------------------- launch -------------------------
extern "C" void kernel_launch(void* const* d_in, const int* in_sizes, int n_in,
                              void* d_out, int out_size, void* d_ws, size_t ws_size,
                              hipStream_t stream) {
    if (ws_size < WS_NEED) return;

    const float* x_cv = (const float*)d_in[0];
    const float* pv_init = (const float*)d_in[1];
    const int* scen = (const int*)d_in[2];
    const float* embt = (const float*)d_in[3];
    const float* Wih0 = (const float*)d_in[4];
    const float* Whh0 = (const float*)d_in[5];
    const float* bih0 = (const float*)d_in[6];
    const float* bhh0 = (const float*)d_in[7];
    const float* Wih1 = (const float*)d_in[8];
    const float* Whh1 = (const float*)d_in[9];
    const float* bih1 = (const float*)d_in[10];
    const float* bhh1 = (const float*)d_in[11];
    const float* fc1w = (const float*)d_in[12];
    const float* fc1b = (const float*)d_in[13];
    const float* fc2w = (const float*)d_in[14];
    const float* fc2b = (const float*)d_in[15];

    char* ws = (char*)d_ws;

    prep_w<<<3232, 256, 0, stream>>>(Wih0, Whh0, Wih1, Whh1, ws);
    prep_fc<<<132, 256, 0, stream>>>(fc1w, fc2w, ws);

    lstm_main<<<256, 512, 0, stream>>>(x_cv, pv_init, scen, embt, Wih0, bih0, bhh0,
                                       bih1, bhh1, fc1b, fc2b, ws, (float*)d_out);
}

// Round 4
// 20841.814 us; speedup vs baseline: 1.0410x; 1.0410x over previous
//
#include <hip/hip_runtime.h>
#include <hip/hip_bf16.h>

// =====================================================================
// PlantLSTM R4: R3 structure, FENCE-FREE sync.
//  - R2/R3 post-mortem: agent-scope acquire/release FENCES compile to
//    buffer_inv / buffer_wbl2 (whole-L2 maintenance) on gfx9xx. 256 WGs
//    x 6 fences/step = constant L2 invalidation -> 112MB refetch storm
//    and ~42us/step. Fix: relaxed sc1 atomics (IC-coherent per-access,
//    no cache ops) + wave-level `s_waitcnt vmcnt(0)` for store->flag
//    ordering + compiler barriers. No fences anywhere in the loop.
//  - Everything else identical to R3: 16 groups x 16 WGs, weights in
//    LDS, exact-match ==t+1 flags, 2-slot parity ring, pipelined
//    gathers (h0 RT under L1 h1-half, h1 RT under L0(t+1), pv as L0's
//    last chunk).
// =====================================================================

#define TSTEPS 512
#define NIN    32

typedef _Float16 h2 __attribute__((ext_vector_type(2)));
typedef unsigned long long ull;

#if __has_builtin(__builtin_amdgcn_fdot2)
#define FDOT2(a, b, c) __builtin_amdgcn_fdot2((a), (b), (c), false)
#else
#define FDOT2(a, b, c) ((c) + (float)(a).x * (float)(b).x + (float)(a).y * (float)(b).y)
#endif

__device__ __forceinline__ float sigm(float x) { return 1.0f / (1.0f + __expf(-x)); }
__device__ __forceinline__ float tanhf_(float x) {
    float e = __expf(2.0f * x);
    return 1.0f - 2.0f / (e + 1.0f);
}

// ---- workspace layout (bytes) ----
#define W0T_OFF 0u
#define W1T_OFF 606208u
#define F1T_OFF 1654784u
#define F2T_OFF 1720320u
#define HX0_OFF 2097152u
#define HX1_OFF 2359296u
#define PVX_OFF 2621440u
#define FLG_OFF 2629632u
#define WS_NEED 2678784u

#define W0S 592
#define W1S 1040
#define X0S 608
#define X1S 1040

// ------------------------- prep kernels (unchanged) -------------------------
__global__ void prep_w(const float* __restrict__ Wih0, const float* __restrict__ Whh0,
                       const float* __restrict__ Wih1, const float* __restrict__ Whh1,
                       char* __restrict__ ws) {
    int gid = blockIdx.x * 256 + threadIdx.x;
    _Float16* w0 = (_Float16*)(ws + W0T_OFF);
    _Float16* w1 = (_Float16*)(ws + W1T_OFF);
    if (gid < 16 * 64 * 296) {
        int k = gid % 296;
        int rest = gid / 296;
        int rl = rest & 63, j = rest >> 6;
        int row = (rl >> 4) * 256 + j * 16 + (rl & 15);
        float v;
        if (k < 32) v = Wih0[row * 72 + k];
        else if (k < 288) v = Whh0[row * 256 + (k - 32)];
        else v = Wih0[row * 72 + 32 + (k - 288)];
        w0[(j * 64 + rl) * 296 + k] = (_Float16)v;
    } else {
        int gid2 = gid - 16 * 64 * 296;
        if (gid2 < 16 * 64 * 512) {
            int k = gid2 & 511;
            int rest = gid2 >> 9;
            int rl = rest & 63, j = rest >> 6;
            int row = (rl >> 4) * 256 + j * 16 + (rl & 15);
            float v = (k < 256) ? Wih1[row * 256 + k] : Whh1[row * 256 + (k - 256)];
            w1[(j * 64 + rl) * 512 + k] = (_Float16)v;
        }
    }
}

__global__ void prep_fc(const float* __restrict__ fc1w, const float* __restrict__ fc2w,
                        char* __restrict__ ws) {
    int gid = blockIdx.x * 256 + threadIdx.x;
    _Float16* f1 = (_Float16*)(ws + F1T_OFF);
    _Float16* f2 = (_Float16*)(ws + F2T_OFF);
    if (gid < 32768) {
        int e = gid & 63, ks = (gid >> 6) & 3, r = gid >> 8;
        f1[gid] = (_Float16)fc1w[r * 256 + ks * 64 + e];
    } else if (gid < 32768 + 1024) {
        int i = gid - 32768;
        f2[i] = (_Float16)fc2w[i];
    }
}

// ------------------------- sync helpers (fence-free) -------------------------
// Post: data stores (sc1, IC-coherent) must complete before flag store issues.
// s_waitcnt vmcnt(0) is wave-level and exec-mask independent; the "memory"
// clobber stops the compiler moving the stores across it. NO buffer_wbl2.
__device__ __forceinline__ void post_flag(unsigned* f, unsigned v) {
    asm volatile("s_waitcnt vmcnt(0)" ::: "memory");
    __hip_atomic_store(f, v, __ATOMIC_RELAXED, __HIP_MEMORY_SCOPE_AGENT);
}
// Poll: relaxed sc1 loads always observe the IC — no staleness, no valve.
__device__ __forceinline__ void poll_flag(unsigned* f, unsigned want) {
    while (__hip_atomic_load(f, __ATOMIC_RELAXED, __HIP_MEMORY_SCOPE_AGENT) != want) {}
}
// Consumer-side compiler barrier only (HW issues in order; sc1 loads hit IC).
#define FENCE_ACQ() asm volatile("" ::: "memory")

// ------------------------- gate accumulation -------------------------
__device__ __forceinline__ void accum(const char* __restrict__ w, int WS,
                                      const char* __restrict__ x, int XS,
                                      int c0, int cstep, int cend,
                                      float* g, int lane) {
    float acc[16];
#pragma unroll
    for (int b = 0; b < 16; ++b) acc[b] = 0.0f;
    for (int c = c0; c < cend; c += cstep) {
        float4 wv4 = *(const float4*)(w + lane * WS + c * 16);
        h2 a0 = __builtin_bit_cast(h2, wv4.x), a1 = __builtin_bit_cast(h2, wv4.y);
        h2 a2 = __builtin_bit_cast(h2, wv4.z), a3 = __builtin_bit_cast(h2, wv4.w);
#pragma unroll
        for (int b = 0; b < 16; ++b) {
            float4 xv = *(const float4*)(x + b * XS + c * 16);
            acc[b] = FDOT2(a0, __builtin_bit_cast(h2, xv.x), acc[b]);
            acc[b] = FDOT2(a1, __builtin_bit_cast(h2, xv.y), acc[b]);
            acc[b] = FDOT2(a2, __builtin_bit_cast(h2, xv.z), acc[b]);
            acc[b] = FDOT2(a3, __builtin_bit_cast(h2, xv.w), acc[b]);
        }
    }
#pragma unroll
    for (int b = 0; b < 16; ++b) atomicAdd(&g[b * 64 + lane], acc[b]);
}

// ------------------------- main kernel -------------------------
__global__ __launch_bounds__(512) void lstm_main(
    const float* __restrict__ x_cv, const float* __restrict__ pv_init,
    const int* __restrict__ scen, const float* __restrict__ emb_table,
    const float* __restrict__ Wih0, const float* __restrict__ b_ih0,
    const float* __restrict__ b_hh0, const float* __restrict__ b_ih1,
    const float* __restrict__ b_hh1, const float* __restrict__ fc1_b,
    const float* __restrict__ fc2_b, char* __restrict__ ws,
    float* __restrict__ out) {
    struct __align__(16) SM {
        char w0[64 * W0S];
        char w1[64 * W1S];
        char xt0[16 * X0S];
        char xt1[16 * X1S];
        float gates0[16][64];
        float gates1[16][64];
        float biasE[16][64];
        float bias1[64];
        _Float16 htmp[16][16];
        float embs[16][32];
        float fc1o[128];
        int scen_l[16];
    };
    __shared__ SM sm;

    const int tid = threadIdx.x;
    const int lane = tid & 63;
    const int wv = tid >> 6;
    const int bid = blockIdx.x;
    const int g = (bid & 7) * 2 + ((bid >> 3) & 1);
    const int j = bid >> 4;
    const int B0 = g * 16;

    const char* w0g = ws + W0T_OFF + (unsigned)j * (64u * 296u * 2u);
    const char* w1g = ws + W1T_OFF + (unsigned)j * (64u * 512u * 2u);
    ull* hx0 = (ull*)(ws + HX0_OFF) + (unsigned)g * 2u * 16u * 64u;
    ull* hx1 = (ull*)(ws + HX1_OFF) + (unsigned)g * 2u * 16u * 64u;
    ull* pvx = (ull*)(ws + PVX_OFF) + (unsigned)g * 2u * 16u * 2u;
    unsigned* flg = (unsigned*)(ws + FLG_OFF) + (unsigned)g * 16u * 3u * 16u;

    // ---- phase 0 ----
    if (tid < 16) sm.scen_l[tid] = scen[B0 + tid];
    if (tid == 0) {
        __hip_atomic_store(&flg[(j * 3 + 0) * 16], 0u, __ATOMIC_RELAXED, __HIP_MEMORY_SCOPE_AGENT);
        __hip_atomic_store(&flg[(j * 3 + 1) * 16], 0u, __ATOMIC_RELAXED, __HIP_MEMORY_SCOPE_AGENT);
        __hip_atomic_store(&flg[(j * 3 + 2) * 16], 0u, __ATOMIC_RELAXED, __HIP_MEMORY_SCOPE_AGENT);
    }
    __syncthreads();

    // ---- phase 1: embs, zero xt, weights -> LDS ----
    {
        int b = tid >> 5, e = tid & 31;
        sm.embs[b][e] = emb_table[sm.scen_l[b] * 32 + e];
    }
    for (int idx = tid; idx < (16 * X0S) / 8; idx += 512) ((ull*)sm.xt0)[idx] = 0ull;
    for (int idx = tid; idx < (16 * X1S) / 8; idx += 512) ((ull*)sm.xt1)[idx] = 0ull;
    for (int idx = tid; idx < 64 * 37; idx += 512) {
        int r = idx / 37, c = idx - r * 37;
        *(float4*)(&sm.w0[r * W0S + c * 16]) = *(const float4*)(w0g + r * 592 + c * 16);
    }
    for (int idx = tid; idx < 64 * 64; idx += 512) {
        int r = idx >> 6, c = idx & 63;
        *(float4*)(&sm.w1[r * W1S + c * 16]) = *(const float4*)(w1g + r * 1024 + c * 16);
    }
    __syncthreads();

    // ---- phase 2: biases, FC register weights ----
    for (int idx = tid; idx < 1024; idx += 512) {
        int b = idx >> 6, rl = idx & 63;
        int row = (rl >> 4) * 256 + j * 16 + (rl & 15);
        float s = b_ih0[row] + b_hh0[row];
        for (int e = 0; e < 32; ++e) s += sm.embs[b][e] * Wih0[row * 72 + 40 + e];
        sm.biasE[b][rl] = s;
    }
    if (tid < 64) {
        int row = (tid >> 4) * 256 + j * 16 + (tid & 15);
        sm.bias1[tid] = b_ih1[row] + b_hh1[row];
    }
    float4 f1w[8];
    {
        const char* f1g = ws + F1T_OFF + (unsigned)tid * 128u;
#pragma unroll
        for (int q = 0; q < 8; ++q) f1w[q] = *(const float4*)(f1g + q * 16);
    }
    float f2w[16];
    if (wv == 0) {
        int jo = lane >> 3, ks2 = lane & 7;
        const _Float16* f2g = (const _Float16*)(ws + F2T_OFF) + jo * 128 + ks2 * 16;
#pragma unroll
        for (int q = 0; q < 16; ++q) f2w[q] = (float)f2g[q];
    }
    const float fc2b_r = (wv == 0) ? fc2_b[lane >> 3] : 0.0f;
    const float fc1b_r = fc1_b[tid >> 2];
    float c0 = 0.0f, c1 = 0.0f;
    __syncthreads();

    // ---- prologue ----
    for (int idx = tid; idx < 1024; idx += 512) {
        int b = idx >> 6, rl = idx & 63;
        sm.gates0[b][rl] = sm.biasE[b][rl];
        sm.gates1[b][rl] = sm.bias1[rl];
    }
    {
        int b = tid >> 5, k = tid & 31;
        float xv = x_cv[((B0 + b) * TSTEPS + 0) * NIN + k];
        *(_Float16*)(&sm.xt0[b * X0S + k * 2]) = (_Float16)xv;
    }
    __syncthreads();
    accum(sm.w0, W0S, sm.xt0, X0S, wv, 8, 36, &sm.gates0[0][0], lane);

    // ==================== time loop ====================
    for (int t = 0; t < TSTEPS; ++t) {
        const int par = t & 1;

        // ---- head: pv(t-1) as L0's final chunk (wave0 only) ----
        if (wv == 0) {
            if (t == 0) {
                int b = lane >> 2, p = lane & 3;
                h2 v;
                v.x = (_Float16)pv_init[(B0 + b) * 8 + p * 2];
                v.y = (_Float16)pv_init[(B0 + b) * 8 + p * 2 + 1];
                *(h2*)(&sm.xt0[b * X0S + 576 + p * 4]) = v;
            } else {
                if (lane < 16) poll_flag(&flg[(lane * 3 + 2) * 16], (unsigned)t);
                FENCE_ACQ();
                if (lane < 32) {
                    int b = lane >> 1, half = lane & 1;
                    int pp = (t - 1) & 1;
                    ull v = __hip_atomic_load(&pvx[(pp * 16 + b) * 2 + half],
                                              __ATOMIC_RELAXED, __HIP_MEMORY_SCOPE_AGENT);
                    *(ull*)(&sm.xt0[b * X0S + 576 + half * 8]) = v;
                }
            }
            accum(sm.w0, W0S, sm.xt0, X0S, 36, 8, 37, &sm.gates0[0][0], lane);
        }
        __syncthreads();  // B1

        // ---- cell 0 ----
        if (tid < 256) {
            int ui = tid & 15, b = tid >> 4;
            float gi = sm.gates0[b][ui], gf = sm.gates0[b][16 + ui];
            float gc = sm.gates0[b][32 + ui], go = sm.gates0[b][48 + ui];
            c0 = sigm(gf) * c0 + sigm(gi) * tanhf_(gc);
            sm.htmp[b][ui] = (_Float16)(sigm(go) * tanhf_(c0));
        }
        __syncthreads();  // B2

        // ---- post h0; stage x(t+1); L1 h1(t-1)-half; poll h0 ----
        if (wv == 0) {
            ull v = *(const ull*)(&sm.htmp[lane >> 2][(lane & 3) * 4]);
            __hip_atomic_store(&hx0[(par * 16 + j) * 64 + lane], v, __ATOMIC_RELAXED,
                               __HIP_MEMORY_SCOPE_AGENT);
            if (lane == 0) post_flag(&flg[(j * 3 + 0) * 16], (unsigned)(t + 1));
        }
        if (t < TSTEPS - 1) {
            int b = tid >> 5, k = tid & 31;
            float xv = x_cv[((B0 + b) * TSTEPS + t + 1) * NIN + k];
            *(_Float16*)(&sm.xt0[b * X0S + k * 2]) = (_Float16)xv;
        }
        accum(sm.w1, W1S, sm.xt1, X1S, 32 + wv, 8, 64, &sm.gates1[0][0], lane);
        if (wv == 0) {
            if (lane < 16) poll_flag(&flg[(lane * 3 + 0) * 16], (unsigned)(t + 1));
            FENCE_ACQ();
        }
        __syncthreads();  // B3

        // ---- gather h0 -> xt1[0:256] & xt0 h0-part; gates0 <- biasE ----
        for (int idx = tid; idx < 1024; idx += 512) {
            int jj = idx >> 6, l = idx & 63;
            ull v = __hip_atomic_load(&hx0[(par * 16 + jj) * 64 + l], __ATOMIC_RELAXED,
                                      __HIP_MEMORY_SCOPE_AGENT);
            int b = l >> 2, u = jj * 16 + (l & 3) * 4;
            *(ull*)(&sm.xt1[b * X1S + u * 2]) = v;
            *(ull*)(&sm.xt0[b * X0S + (32 + u) * 2]) = v;
        }
        for (int idx = tid; idx < 1024; idx += 512) {
            int b = idx >> 6, rl = idx & 63;
            sm.gates0[b][rl] = sm.biasE[b][rl];
        }
        __syncthreads();  // B4

        // ---- L1 h0-half ----
        accum(sm.w1, W1S, sm.xt1, X1S, wv, 8, 32, &sm.gates1[0][0], lane);
        __syncthreads();  // B5

        // ---- cell 1 ----
        if (tid < 256) {
            int ui = tid & 15, b = tid >> 4;
            float gi = sm.gates1[b][ui], gf = sm.gates1[b][16 + ui];
            float gc = sm.gates1[b][32 + ui], go = sm.gates1[b][48 + ui];
            c1 = sigm(gf) * c1 + sigm(gi) * tanhf_(gc);
            sm.htmp[b][ui] = (_Float16)(sigm(go) * tanhf_(c1));
        }
        __syncthreads();  // B6

        // ---- post h1; gates1 <- bias1; L0(t+1) x+h0 chunks; poll h1 ----
        if (wv == 0) {
            ull v = *(const ull*)(&sm.htmp[lane >> 2][(lane & 3) * 4]);
            __hip_atomic_store(&hx1[(par * 16 + j) * 64 + lane], v, __ATOMIC_RELAXED,
                               __HIP_MEMORY_SCOPE_AGENT);
            if (lane == 0) post_flag(&flg[(j * 3 + 1) * 16], (unsigned)(t + 1));
        }
        for (int idx = tid; idx < 1024; idx += 512) {
            int b = idx >> 6, rl = idx & 63;
            sm.gates1[b][rl] = sm.bias1[rl];
        }
        if (t < TSTEPS - 1) {
            if (wv > 0) accum(sm.w0, W0S, sm.xt0, X0S, wv - 1, 7, 35, &sm.gates0[0][0], lane);
            else accum(sm.w0, W0S, sm.xt0, X0S, 35, 7, 36, &sm.gates0[0][0], lane);
        }
        if (wv == 0) {
            if (lane < 16) poll_flag(&flg[(lane * 3 + 1) * 16], (unsigned)(t + 1));
            FENCE_ACQ();
        }
        __syncthreads();  // B7

        // ---- gather h1 -> xt1[256:512] ----
        for (int idx = tid; idx < 1024; idx += 512) {
            int jj = idx >> 6, l = idx & 63;
            ull v = __hip_atomic_load(&hx1[(par * 16 + jj) * 64 + l], __ATOMIC_RELAXED,
                                      __HIP_MEMORY_SCOPE_AGENT);
            int b = l >> 2, u = jj * 16 + (l & 3) * 4;
            *(ull*)(&sm.xt1[b * X1S + (256 + u) * 2]) = v;
        }
        __syncthreads();  // B8

        // ---- FC1 (own batch j) ----
        {
            int row = tid >> 2, ks = tid & 3;
            float a = 0.0f;
#pragma unroll
            for (int q = 0; q < 8; ++q) {
                float4 xv = *(const float4*)(&sm.xt1[j * X1S + (256 + ks * 64 + q * 8) * 2]);
                a = FDOT2(__builtin_bit_cast(h2, f1w[q].x), __builtin_bit_cast(h2, xv.x), a);
                a = FDOT2(__builtin_bit_cast(h2, f1w[q].y), __builtin_bit_cast(h2, xv.y), a);
                a = FDOT2(__builtin_bit_cast(h2, f1w[q].z), __builtin_bit_cast(h2, xv.z), a);
                a = FDOT2(__builtin_bit_cast(h2, f1w[q].w), __builtin_bit_cast(h2, xv.w), a);
            }
            a += __shfl_xor(a, 1);
            a += __shfl_xor(a, 2);
            if (ks == 0) sm.fc1o[row] = fmaxf(a + fc1b_r, 0.0f);
        }
        __syncthreads();  // B9

        // ---- FC2 (wave0) -> out + pv post ----
        if (wv == 0) {
            int jo = lane >> 3, ks2 = lane & 7;
            float a = 0.0f;
#pragma unroll
            for (int q = 0; q < 4; ++q) {
                float4 xv = *(const float4*)(&sm.fc1o[ks2 * 16 + q * 4]);
                a += f2w[q * 4 + 0] * xv.x + f2w[q * 4 + 1] * xv.y +
                     f2w[q * 4 + 2] * xv.z + f2w[q * 4 + 3] * xv.w;
            }
            a += __shfl_xor(a, 1);
            a += __shfl_xor(a, 2);
            a += __shfl_xor(a, 4);
            float av = a + fc2b_r;
            if (ks2 == 0) out[((B0 + j) * TSTEPS + t) * 8 + jo] = av;
            float p0 = __shfl(av, 0), p1 = __shfl(av, 8), p2 = __shfl(av, 16), p3 = __shfl(av, 24);
            float p4 = __shfl(av, 32), p5 = __shfl(av, 40), p6 = __shfl(av, 48), p7 = __shfl(av, 56);
            if (lane == 0) {
                h2 q0, q1, q2, q3;
                q0.x = (_Float16)p0; q0.y = (_Float16)p1;
                q1.x = (_Float16)p2; q1.y = (_Float16)p3;
                q2.x = (_Float16)p4; q2.y = (_Float16)p5;
                q3.x = (_Float16)p6; q3.y = (_Float16)p7;
                ull v0 = ((ull)__builtin_bit_cast(unsigned, q1) << 32) |
                         __builtin_bit_cast(unsigned, q0);
                ull v1 = ((ull)__builtin_bit_cast(unsigned, q3) << 32) |
                         __builtin_bit_cast(unsigned, q2);
                __hip_atomic_store(&pvx[(par * 16 + j) * 2 + 0], v0, __ATOMIC_RELAXED,
                                   __HIP_MEMORY_SCOPE_AGENT);
                __hip_atomic_store(&pvx[(par * 16 + j) * 2 + 1], v1, __ATOMIC_RELAXED,
                                   __HIP_MEMORY_SCOPE_AGENT);
                post_flag(&flg[(j * 3 + 2) * 16], (unsigned)(t + 1));
            }
        }
    }
}

// ------------------------- launch -------------------------
extern "C" void kernel_launch(void* const* d_in, const int* in_sizes, int n_in,
                              void* d_out, int out_size, void* d_ws, size_t ws_size,
                              hipStream_t stream) {
    if (ws_size < WS_NEED) return;

    const float* x_cv = (const float*)d_in[0];
    const float* pv_init = (const float*)d_in[1];
    const int* scen = (const int*)d_in[2];
    const float* embt = (const float*)d_in[3];
    const float* Wih0 = (const float*)d_in[4];
    const float* Whh0 = (const float*)d_in[5];
    const float* bih0 = (const float*)d_in[6];
    const float* bhh0 = (const float*)d_in[7];
    const float* Wih1 = (const float*)d_in[8];
    const float* Whh1 = (const float*)d_in[9];
    const float* bih1 = (const float*)d_in[10];
    const float* bhh1 = (const float*)d_in[11];
    const float* fc1w = (const float*)d_in[12];
    const float* fc1b = (const float*)d_in[13];
    const float* fc2w = (const float*)d_in[14];
    const float* fc2b = (const float*)d_in[15];

    char* ws = (char*)d_ws;

    prep_w<<<3232, 256, 0, stream>>>(Wih0, Whh0, Wih1, Whh1, ws);
    prep_fc<<<132, 256, 0, stream>>>(fc1w, fc2w, ws);

    lstm_main<<<256, 512, 0, stream>>>(x_cv, pv_init, scen, embt, Wih0, bih0, bhh0,
                                       bih1, bhh1, fc1b, fc2b, ws, (float*)d_out);
}